// Round 1
// baseline (99.163 us; speedup 1.0000x reference)
//
#include <hip/hip_runtime.h>

// SIMDIS: mean cosine similarity -> bottom-100 argsort -> gather.
// Key identity: mean_sim_i = (x_i . s) / (n_i * N) with s = sum_j x_j / n_j.
// Everything accumulated in double (memory-bound anyway) so our ranking is the
// true ranking; deterministic reductions (no FP atomics) so validate == replay.

#define N 8192
#define D 512
#define K 100
#define NCHUNK 64   // row chunks for column-sum partials (8192/128)

typedef unsigned long long u64;
typedef unsigned int u32;

__device__ __forceinline__ u32 f32_sortable(float f) {
    u32 u = __float_as_uint(f);
    return (u & 0x80000000u) ? ~u : (u | 0x80000000u);
}

// One wave (64 lanes) per row: inv_n[row] = 1/||x_row||, double precision.
__global__ void norms_k(const float* __restrict__ x, double* __restrict__ inv_n) {
    int lane = threadIdx.x & 63;
    int row  = (blockIdx.x << 2) + (threadIdx.x >> 6);
    const float4* xr = (const float4*)(x + (size_t)row * D);
    float4 a = xr[lane];
    float4 b = xr[lane + 64];
    double s = (double)a.x * a.x + (double)a.y * a.y + (double)a.z * a.z + (double)a.w * a.w
             + (double)b.x * b.x + (double)b.y * b.y + (double)b.z * b.z + (double)b.w * b.w;
    for (int off = 32; off > 0; off >>= 1) s += __shfl_down(s, off);
    if (lane == 0) inv_n[row] = 1.0 / sqrt(s);
}

// part[chunk][col] = sum over 128 rows of x[r][col] * inv_n[r]. Deterministic.
__global__ void colsum_k(const float* __restrict__ x, const double* __restrict__ inv_n,
                         double* __restrict__ part) {
    int col   = blockIdx.x * 256 + threadIdx.x;
    int chunk = blockIdx.y;
    int r0    = chunk * 128;
    double acc = 0.0;
    for (int r = r0; r < r0 + 128; ++r)
        acc += (double)x[(size_t)r * D + col] * inv_n[r];
    part[(size_t)chunk * D + col] = acc;
}

// s[col] = sum over chunks of part[chunk][col].
__global__ void reduce_s_k(const double* __restrict__ part, double* __restrict__ s) {
    int col = blockIdx.x * 64 + threadIdx.x;
    double acc = 0.0;
    for (int c = 0; c < NCHUNK; ++c) acc += part[(size_t)c * D + col];
    s[col] = acc;
}

// One wave per row: score = (x_row . s) * inv_n[row]  (monotone in mean_sim).
// Pack sortable-f32(score) << 32 | row  -> stable ascending argsort via u64 compare.
__global__ void score_k(const float* __restrict__ x, const double* __restrict__ inv_n,
                        const double* __restrict__ s, u64* __restrict__ keys) {
    int lane = threadIdx.x & 63;
    int row  = (blockIdx.x << 2) + (threadIdx.x >> 6);
    const float4* xr = (const float4*)(x + (size_t)row * D);
    float4 a = xr[lane];
    float4 b = xr[lane + 64];
    int c0 = lane * 4, c1 = (lane + 64) * 4;
    double acc = (double)a.x * s[c0]     + (double)a.y * s[c0 + 1]
               + (double)a.z * s[c0 + 2] + (double)a.w * s[c0 + 3]
               + (double)b.x * s[c1]     + (double)b.y * s[c1 + 1]
               + (double)b.z * s[c1 + 2] + (double)b.w * s[c1 + 3];
    for (int off = 32; off > 0; off >>= 1) acc += __shfl_down(acc, off);
    if (lane == 0) {
        float sc = (float)(acc * inv_n[row]);
        keys[row] = ((u64)f32_sortable(sc) << 32) | (u32)row;
    }
}

// In-LDS bitonic sort, ascending, blockDim.x == NELEM (power of 2).
template <int NELEM>
__device__ __forceinline__ void bitonic_sort(u64* lds) {
    int t = threadIdx.x;
    for (int k = 2; k <= NELEM; k <<= 1) {
        for (int j = k >> 1; j > 0; j >>= 1) {
            int ixj = t ^ j;
            if (ixj > t) {
                u64 a = lds[t], b = lds[ixj];
                bool up = ((t & k) == 0);
                if ((a > b) == up) { lds[t] = b; lds[ixj] = a; }
            }
            __syncthreads();
        }
    }
}

// Stage 1: 8 blocks x 1024 keys; keep each block's bottom 128 (sorted).
// Any global bottom-100 element has rank < 128 within its own block.
__global__ __launch_bounds__(1024) void select1_k(const u64* __restrict__ keys,
                                                  u64* __restrict__ cand) {
    __shared__ u64 lds[1024];
    int t = threadIdx.x;
    lds[t] = keys[blockIdx.x * 1024 + t];
    __syncthreads();
    bitonic_sort<1024>(lds);
    if (t < 128) cand[blockIdx.x * 128 + t] = lds[t];
}

// Stage 2: sort the 1024 candidates; first 100 are the answer, in order.
__global__ __launch_bounds__(1024) void select2_k(const u64* __restrict__ cand,
                                                  int* __restrict__ sel,
                                                  float* __restrict__ out_idx) {
    __shared__ u64 lds[1024];
    int t = threadIdx.x;
    lds[t] = cand[t];
    __syncthreads();
    bitonic_sort<1024>(lds);
    if (t < K) {
        int idx = (int)(u32)(lds[t] & 0xffffffffu);
        sel[t] = idx;
        out_idx[t] = (float)idx;   // indices exactly representable in f32
    }
}

// Gather the 100 selected rows (bit-exact copy). 128 threads * float4 = 512 f32.
__global__ void gather_k(const float* __restrict__ x, const int* __restrict__ sel,
                         float* __restrict__ out) {
    int g = blockIdx.x;
    int idx = sel[g];
    const float4* src = (const float4*)(x + (size_t)idx * D);
    float4* dst = (float4*)(out + (size_t)g * D);
    dst[threadIdx.x] = src[threadIdx.x];
}

extern "C" void kernel_launch(void* const* d_in, const int* in_sizes, int n_in,
                              void* d_out, int out_size, void* d_ws, size_t ws_size,
                              hipStream_t stream) {
    const float* x = (const float*)d_in[0];
    float* out = (float*)d_out;          // [K*D gathered rows][K indices]

    // ws layout (all 8B-aligned), ~398 KB total:
    char* ws = (char*)d_ws;
    double* inv_n = (double*)(ws);            //  8192 * 8 = 65536
    double* s     = (double*)(ws + 65536);    //   512 * 8 =  4096
    u64*    keys  = (u64*)   (ws + 69632);    //  8192 * 8 = 65536
    u64*    cand  = (u64*)   (ws + 135168);   //  1024 * 8 =  8192
    int*    sel   = (int*)   (ws + 143360);   //   100 * 4 (pad to 512)
    double* part  = (double*)(ws + 143872);   // 64 * 512 * 8 = 262144

    norms_k  <<<N / 4, 256, 0, stream>>>(x, inv_n);
    colsum_k <<<dim3(2, NCHUNK), 256, 0, stream>>>(x, inv_n, part);
    reduce_s_k<<<8, 64, 0, stream>>>(part, s);
    score_k  <<<N / 4, 256, 0, stream>>>(x, inv_n, s, keys);
    select1_k<<<8, 1024, 0, stream>>>(keys, cand);
    select2_k<<<1, 1024, 0, stream>>>(cand, sel, out + (size_t)K * D);
    gather_k <<<K, 128, 0, stream>>>(x, sel, out);
}